// Round 1
// 346.751 us; speedup vs baseline: 1.0100x; 1.0100x over previous
//
#include <hip/hip_runtime.h>
#include <cstdint>
#include <cstddef>

// ---------------- workspace layout ----------------
// xp  : [32][58][58][256] bf16  (NHWC, spatial halo of zeros)  = 55,115,776 B
// Wb  : [256][2304] bf16 (sign(w) as +-1; k = tap*256 + c)     =  1,179,648 B
// alpha: [256] f32                                              =      1,024 B
#define XP_BYTES 55115776ull
#define WB_OFF   55115776ull
#define AL_OFF   (WB_OFF + 1179648ull)

typedef __bf16 bf16x8 __attribute__((ext_vector_type(8)));
typedef float  f32x4  __attribute__((ext_vector_type(4)));
typedef unsigned short u16x8 __attribute__((ext_vector_type(8)));

static __device__ __forceinline__ unsigned short f2bf(float f) {
  union { float f; unsigned int u; } v; v.f = f;
  unsigned int u = v.u;
  u += 0x7FFFu + ((u >> 16) & 1u);   // RNE
  return (unsigned short)(u >> 16);
}

static __device__ __forceinline__ void async16(void* lds, const void* g) {
  __builtin_amdgcn_global_load_lds(
      (const __attribute__((address_space(1))) unsigned int*)g,
      (__attribute__((address_space(3))) unsigned int*)lds, 16, 0, 0);
}

// ---------------- weight prep: alpha[o] + sign(w) in bf16, k = tap*256+c ----
__global__ void prep_w(const float* __restrict__ w, unsigned short* __restrict__ wb,
                       float* __restrict__ alpha) {
  const int o = blockIdx.x, c = threadIdx.x;
  const float* wr = w + (size_t)(o * 256 + c) * 9;
  float s = 0.f;
#pragma unroll
  for (int tap = 0; tap < 9; ++tap) {
    float v = wr[tap];
    s += fabsf(v);
    unsigned short sg = (v > 0.f) ? 0x3F80u : ((v < 0.f) ? 0xBF80u : 0u);
    wb[(size_t)o * 2304 + tap * 256 + c] = sg;
  }
  __shared__ float red[256];
  red[c] = s;
  __syncthreads();
  for (int d = 128; d > 0; d >>= 1) {
    if (c < d) red[c] += red[c + d];
    __syncthreads();
  }
  if (c == 0) alpha[o] = red[0] * (1.f / 2304.f);
}

// ---------------- halo zeroing: rows 0/57 full width, cols 0/57 rows 1..56 --
__global__ void zero_halo(unsigned short* __restrict__ xp) {
  const int n = blockIdx.x;
  const int t = threadIdx.x;                       // 1024 threads
  uint32_t* base = (uint32_t*)(xp + (size_t)n * 58 * 58 * 256);
  uint32_t* r57 = base + 57 * 7424;                // 58*256 ushort = 7424 u32/row
  for (int i = t; i < 7424; i += 1024) { base[i] = 0; r57[i] = 0; }
  for (int i = t; i < 7168; i += 1024) {           // 56 rows * 128 u32 per col
    const int r = i >> 7, c = i & 127;
    base[(size_t)((r + 1) * 58) * 128 + c] = 0;
    base[(size_t)((r + 1) * 58 + 57) * 128 + c] = 0;
  }
}

// ---------------- x prep: NCHW f32 -> NHWC bf16 (interior), LDS transpose ---
// grid = 32 * 49 blocks (one per (n, 64-pixel tile)), 256 threads.
// Read: 16-lane groups read 256 B contiguous runs along the pixel axis.
// LDS tile [64 pix][256 ch] bf16 (32 KB), channel index XOR-swizzled by pixel
// bits to spread the 2B scatter writes across banks.
// Write: 32-lane groups write 512 B contiguous NHWC channel runs per pixel.
__global__ void prep_x(const float* __restrict__ x, unsigned short* __restrict__ xp) {
  __shared__ unsigned short tile[64 * 256];
  const int bx = blockIdx.x;
  const int n = bx / 49, pt = bx % 49;
  const int p0 = pt * 64;
  const int tid = threadIdx.x;
  const int f = tid & 15;                  // float4 chunk within 64-pixel run
  const int cg = tid >> 4;                 // channel group 0..15
  const float* xn = x + (size_t)n * 256 * 3136 + p0 + f * 4;

#pragma unroll
  for (int i = 0; i < 16; ++i) {
    const int c = cg + i * 16;
    const float4 v = *(const float4*)(xn + (size_t)c * 3136);
    unsigned short b[4] = {f2bf(v.x), f2bf(v.y), f2bf(v.z), f2bf(v.w)};
#pragma unroll
    for (int j = 0; j < 4; ++j) {
      const int pix = f * 4 + j;
      const int cs = c ^ (((pix >> 2) & 3) << 3) ^ (((pix >> 4) & 3) << 5);
      tile[pix * 256 + cs] = b[j];
    }
  }
  __syncthreads();

  const int c8 = (tid & 31) * 8;
  const int psub = tid >> 5;
#pragma unroll
  for (int pass = 0; pass < 8; ++pass) {
    const int pl = psub + pass * 8;
    const int p = p0 + pl;
    const int h = p / 56, w = p % 56;
    const int cs = c8 ^ (((pl >> 2) & 3) << 3) ^ (((pl >> 4) & 3) << 5);
    const u16x8 v = *(const u16x8*)&tile[pl * 256 + cs];
    *(u16x8*)(xp + ((size_t)(n * 58 + h + 1) * 58 + (w + 1)) * 256 + c8) = v;
  }
}

// ---------------- implicit-GEMM conv: C[o][pix] = Wb * Xp ----------------
// M=256 (2 tiles of 128), N=100352 (784 tiles of 128), K=2304 (72 steps of 32)
// Double-buffered LDS (2 x 16 KB); next K-step's global_load_lds issued before
// current step's ds_read+MFMA; ONE barrier per K-step (drains vmcnt+lgkmcnt).
__global__ __launch_bounds__(256, 2)
void conv_mfma(const unsigned short* __restrict__ xp,
               const unsigned short* __restrict__ wb,
               const float* __restrict__ alpha,
               float* __restrict__ out) {
  __shared__ __align__(16) char lds[32768];

  const int tid = threadIdx.x;
  const int wave = tid >> 6, lane = tid & 63;
  const int wm = wave >> 1, wn = wave & 1;
  const int o0 = (blockIdx.x & 1) * 128;
  const int pix0 = (blockIdx.x >> 1) * 128;

  const int chunk = lane & 3;        // 16B chunk within 64B row
  const int rsub = lane >> 2;        // row within 16-row group

  const char* wbB = (const char*)wb;
  const char* xpB = (const char*)xp;
  const char* gA[2];
  const char* gB[2];
#pragma unroll
  for (int j = 0; j < 2; ++j) {
    const int row = (wave * 2 + j) * 16 + rsub;           // 0..127
    gA[j] = wbB + ((size_t)(o0 + row) * 2304 + chunk * 8) * 2;
    const int pix = pix0 + row;
    const int n = pix / 3136, rem = pix % 3136;
    const int h = rem / 56, w = rem % 56;
    gB[j] = xpB + (size_t)((n * 58 + h) * 58 + w) * 512 + chunk * 16;
  }

  f32x4 acc[4][4];
#pragma unroll
  for (int i = 0; i < 4; ++i)
#pragma unroll
    for (int j = 0; j < 4; ++j) acc[i][j] = (f32x4){0.f, 0.f, 0.f, 0.f};

  const int ar = lane & 15, aq = lane >> 4;

  // k-step ks in [0,72): tap = ks>>3, cc = ks&7
  auto stage = [&](int b, int ks) {
    const int tap = ks >> 3;
    const int tapoff = ((tap / 3) * 58 + (tap % 3)) * 512;
    const int kA = ks * 64;                 // byte offset within Wb row
    const int kB = tapoff + (ks & 7) * 64;  // byte offset into xp
    char* LA = lds + b * 16384;
    char* LB = LA + 8192;
    async16(LA + (wave * 2 + 0) * 1024, gA[0] + kA);
    async16(LA + (wave * 2 + 1) * 1024, gA[1] + kA);
    async16(LB + (wave * 2 + 0) * 1024, gB[0] + kB);
    async16(LB + (wave * 2 + 1) * 1024, gB[1] + kB);
  };

  stage(0, 0);
#pragma unroll 2
  for (int ks = 0; ks < 72; ++ks) {
    const int cur = ks & 1;
    __syncthreads();                       // stage(ks) landed; prev reads done
    if (ks < 71) stage(cur ^ 1, ks + 1);   // prefetch overlaps this step's MFMAs

    const char* LA = lds + cur * 16384;
    const char* LB = LA + 8192;
    bf16x8 af[4], bfr[4];
#pragma unroll
    for (int mi = 0; mi < 4; ++mi)
      af[mi] = *(const bf16x8*)(LA + ((wm * 64 + mi * 16 + ar) * 64 + aq * 16));
#pragma unroll
    for (int ni = 0; ni < 4; ++ni)
      bfr[ni] = *(const bf16x8*)(LB + ((wn * 64 + ni * 16 + ar) * 64 + aq * 16));
#pragma unroll
    for (int mi = 0; mi < 4; ++mi)
#pragma unroll
      for (int ni = 0; ni < 4; ++ni)
        acc[mi][ni] = __builtin_amdgcn_mfma_f32_16x16x32_bf16(af[mi], bfr[ni], acc[mi][ni], 0, 0, 0);
  }

  // epilogue: D[row=o][col=pix], col=lane&15, row=(lane>>4)*4+r ; scale by alpha[o]
  int nc[4], rc[4];
#pragma unroll
  for (int ni = 0; ni < 4; ++ni) {
    const int pix = pix0 + wn * 64 + ni * 16 + ar;
    nc[ni] = pix / 3136; rc[ni] = pix % 3136;
  }
#pragma unroll
  for (int mi = 0; mi < 4; ++mi) {
    const int orow = o0 + wm * 64 + mi * 16 + aq * 4;
    float al[4];
#pragma unroll
    for (int r = 0; r < 4; ++r) al[r] = alpha[orow + r];
#pragma unroll
    for (int ni = 0; ni < 4; ++ni) {
      const size_t base = (size_t)nc[ni] * 802816 + (size_t)orow * 3136 + (size_t)rc[ni];
#pragma unroll
      for (int r = 0; r < 4; ++r)
        out[base + (size_t)r * 3136] = acc[mi][ni][r] * al[r];
    }
  }
}

extern "C" void kernel_launch(void* const* d_in, const int* in_sizes, int n_in,
                              void* d_out, int out_size, void* d_ws, size_t ws_size,
                              hipStream_t stream) {
  const float* x = (const float*)d_in[0];
  const float* w = (const float*)d_in[1];
  char* ws = (char*)d_ws;
  unsigned short* xp  = (unsigned short*)ws;
  unsigned short* wbp = (unsigned short*)(ws + WB_OFF);
  float* alpha = (float*)(ws + AL_OFF);
  float* out = (float*)d_out;

  zero_halo<<<32, 1024, 0, stream>>>(xp);
  prep_w<<<256, 256, 0, stream>>>(w, wbp, alpha);
  prep_x<<<32 * 49, 256, 0, stream>>>(x, xp);
  conv_mfma<<<1568, 256, 0, stream>>>(xp, wbp, alpha, out);
}

// Round 3
// 312.713 us; speedup vs baseline: 1.1199x; 1.1088x over previous
//
#include <hip/hip_runtime.h>
#include <cstdint>
#include <cstddef>

// ---------------- workspace layout ----------------
// xp  : [32][58][58][256] bf16  (NHWC, spatial halo of zeros)  = 55,115,776 B
// Wb  : [256][2304] bf16 (sign(w) as +-1; k = tap*256 + c)     =  1,179,648 B
// alpha: [256] f32                                              =      1,024 B
#define XP_BYTES 55115776ull
#define WB_OFF   55115776ull
#define AL_OFF   (WB_OFF + 1179648ull)

typedef __bf16 bf16x8 __attribute__((ext_vector_type(8)));
typedef float  f32x4  __attribute__((ext_vector_type(4)));
typedef unsigned short u16x8 __attribute__((ext_vector_type(8)));

static __device__ __forceinline__ unsigned short f2bf(float f) {
  union { float f; unsigned int u; } v; v.f = f;
  unsigned int u = v.u;
  u += 0x7FFFu + ((u >> 16) & 1u);   // RNE
  return (unsigned short)(u >> 16);
}

static __device__ __forceinline__ void async16(void* lds, const void* g) {
  __builtin_amdgcn_global_load_lds(
      (const __attribute__((address_space(1))) unsigned int*)g,
      (__attribute__((address_space(3))) unsigned int*)lds, 16, 0, 0);
}

// ---------------- weight prep: alpha[o] + sign(w) in bf16, k = tap*256+c ----
__global__ void prep_w(const float* __restrict__ w, unsigned short* __restrict__ wb,
                       float* __restrict__ alpha) {
  const int o = blockIdx.x, c = threadIdx.x;
  const float* wr = w + (size_t)(o * 256 + c) * 9;
  float s = 0.f;
#pragma unroll
  for (int tap = 0; tap < 9; ++tap) {
    float v = wr[tap];
    s += fabsf(v);
    unsigned short sg = (v > 0.f) ? 0x3F80u : ((v < 0.f) ? 0xBF80u : 0u);
    wb[(size_t)o * 2304 + tap * 256 + c] = sg;
  }
  __shared__ float red[256];
  red[c] = s;
  __syncthreads();
  for (int d = 128; d > 0; d >>= 1) {
    if (c < d) red[c] += red[c + d];
    __syncthreads();
  }
  if (c == 0) alpha[o] = red[0] * (1.f / 2304.f);
}

// ---------------- halo zeroing: rows 0/57 full width, cols 0/57 rows 1..56 --
__global__ void zero_halo(unsigned short* __restrict__ xp) {
  const int n = blockIdx.x;
  const int t = threadIdx.x;                       // 1024 threads
  uint32_t* base = (uint32_t*)(xp + (size_t)n * 58 * 58 * 256);
  uint32_t* r57 = base + 57 * 7424;                // 58*256 ushort = 7424 u32/row
  for (int i = t; i < 7424; i += 1024) { base[i] = 0; r57[i] = 0; }
  for (int i = t; i < 7168; i += 1024) {           // 56 rows * 128 u32 per col
    const int r = i >> 7, c = i & 127;
    base[(size_t)((r + 1) * 58) * 128 + c] = 0;
    base[(size_t)((r + 1) * 58 + 57) * 128 + c] = 0;
  }
}

// ---------------- x prep: NCHW f32 -> NHWC bf16 (interior), LDS transpose ---
__global__ void prep_x(const float* __restrict__ x, unsigned short* __restrict__ xp) {
  __shared__ unsigned short tile[64 * 256];
  const int bx = blockIdx.x;
  const int n = bx / 49, pt = bx % 49;
  const int p0 = pt * 64;
  const int tid = threadIdx.x;
  const int f = tid & 15;                  // float4 chunk within 64-pixel run
  const int cg = tid >> 4;                 // channel group 0..15
  const float* xn = x + (size_t)n * 256 * 3136 + p0 + f * 4;

#pragma unroll
  for (int i = 0; i < 16; ++i) {
    const int c = cg + i * 16;
    const float4 v = *(const float4*)(xn + (size_t)c * 3136);
    unsigned short b[4] = {f2bf(v.x), f2bf(v.y), f2bf(v.z), f2bf(v.w)};
#pragma unroll
    for (int j = 0; j < 4; ++j) {
      const int pix = f * 4 + j;
      const int cs = c ^ (((pix >> 2) & 3) << 3) ^ (((pix >> 4) & 3) << 5);
      tile[pix * 256 + cs] = b[j];
    }
  }
  __syncthreads();

  const int c8 = (tid & 31) * 8;
  const int psub = tid >> 5;
#pragma unroll
  for (int pass = 0; pass < 8; ++pass) {
    const int pl = psub + pass * 8;
    const int p = p0 + pl;
    const int h = p / 56, w = p % 56;
    const int cs = c8 ^ (((pl >> 2) & 3) << 3) ^ (((pl >> 4) & 3) << 5);
    const u16x8 v = *(const u16x8*)&tile[pl * 256 + cs];
    *(u16x8*)(xp + ((size_t)(n * 58 + h + 1) * 58 + (w + 1)) * 256 + c8) = v;
  }
}

// ---------------- implicit-GEMM conv: C[o][pix] = Wb * Xp ----------------
// Block tile 256(o) x 128(pix); 4 waves, wave tile 128x64, acc[8][4].
// K = 2304 = 72 steps of 32. 3-deep LDS pipeline (3 x 24 KB), ONE raw
// s_barrier per step, counted s_waitcnt vmcnt(6) (never 0 in main loop).
// stage(t+2) issued right after barrier(t): targets the buffer consumed at
// step t-1, which every wave finished reading before reaching barrier(t)
// (its t-1 MFMAs issued, and MFMA issue implies the ds_reads landed).
// T2 swizzle per rule #21: LDS dest stays linear (global_load_lds writes
// base+lane*16); the SOURCE chunk is permuted c = (lane&3)^((rsub>>1)&3),
// and fragment reads apply the same XOR: pos = aq^((ar>>1)&3). Bank base
// becomes (ar&1)*16 + pos*4 -> 2 lanes/bank-slot = wave64 minimum (free).
__global__ __launch_bounds__(256, 2)
void conv_mfma(const unsigned short* __restrict__ xp,
               const unsigned short* __restrict__ wb,
               const float* __restrict__ alpha,
               float* __restrict__ out) {
  __shared__ __align__(16) char lds[73728];   // 3 x (16K A + 8K B)

  const int tid = threadIdx.x;
  const int wave = tid >> 6, lane = tid & 63;
  const int wm = wave & 1, wn = wave >> 1;

  // XCD-chunked pixel-tile swizzle: 784 tiles = 8 XCDs x 98 contiguous tiles
  const int ptile = (blockIdx.x & 7) * 98 + (blockIdx.x >> 3);
  const int pix0 = ptile * 128;

  const int rsub  = lane >> 2;                       // row within 16-row group
  const int chunk = (lane & 3) ^ ((rsub >> 1) & 3);  // swizzled 16B chunk

  const char* wbB = (const char*)wb;
  const char* xpB = (const char*)xp;
  const char* gA[4];
  const char* gB[2];
#pragma unroll
  for (int j = 0; j < 4; ++j) {
    const int row = wave * 64 + j * 16 + rsub;            // o row 0..255
    gA[j] = wbB + ((size_t)row * 2304 + chunk * 8) * 2;
  }
#pragma unroll
  for (int j = 0; j < 2; ++j) {
    const int prow = wave * 32 + j * 16 + rsub;           // 0..127
    const int pix = pix0 + prow;
    const int n = pix / 3136, rem = pix % 3136;
    const int h = rem / 56, w = rem % 56;
    gB[j] = xpB + (size_t)((n * 58 + h) * 58 + w) * 512 + chunk * 16;
  }

  f32x4 acc[8][4];
#pragma unroll
  for (int i = 0; i < 8; ++i)
#pragma unroll
    for (int j = 0; j < 4; ++j) acc[i][j] = (f32x4){0.f, 0.f, 0.f, 0.f};

  const int ar = lane & 15, aq = lane >> 4;
  const int axor = ((ar >> 1) & 3) * 16;   // byte XOR for fragment reads

  auto stage = [&](int buf, int ks) {
    const int tap = ks >> 3;
    const int kh = (tap * 11) >> 5;          // tap/3 for tap in 0..8
    const int kw = tap - kh * 3;
    const int kA = ks * 64;                               // bytes into Wb row
    const int kB = (kh * 58 + kw) * 512 + (ks & 7) * 64;  // bytes into xp
    char* base = lds + buf * 24576;
#pragma unroll
    for (int j = 0; j < 4; ++j)
      async16(base + (wave * 4 + j) * 1024, gA[j] + kA);
#pragma unroll
    for (int j = 0; j < 2; ++j)
      async16(base + 16384 + (wave * 2 + j) * 1024, gB[j] + kB);
  };

  auto step = [&](int buf) {
    const char* LA = lds + buf * 24576;
    const char* LB = LA + 16384;
    bf16x8 af[8], bfr[4];
#pragma unroll
    for (int mi = 0; mi < 8; ++mi)
      af[mi] = *(const bf16x8*)(LA + ((wm * 128 + mi * 16 + ar) * 64 + (aq * 16 ^ axor)));
#pragma unroll
    for (int ni = 0; ni < 4; ++ni)
      bfr[ni] = *(const bf16x8*)(LB + ((wn * 64 + ni * 16 + ar) * 64 + (aq * 16 ^ axor)));
    __builtin_amdgcn_s_setprio(1);
#pragma unroll
    for (int mi = 0; mi < 8; ++mi)
#pragma unroll
      for (int ni = 0; ni < 4; ++ni)
        acc[mi][ni] = __builtin_amdgcn_mfma_f32_16x16x32_bf16(af[mi], bfr[ni], acc[mi][ni], 0, 0, 0);
    __builtin_amdgcn_s_setprio(0);
  };

#define ROUND(buf, t)                                   \
  asm volatile("s_waitcnt vmcnt(6)" ::: "memory");      \
  __builtin_amdgcn_s_barrier();                         \
  asm volatile("" ::: "memory");                        \
  stage(((buf) + 2) % 3, (t) + 2);                      \
  step(buf);

  stage(0, 0);
  stage(1, 1);
  for (int t3 = 0; t3 < 69; t3 += 3) {    // t = 0..68
    ROUND(0, t3)
    ROUND(1, t3 + 1)
    ROUND(2, t3 + 2)
  }
  ROUND(0, 69)                            // stages ks=71 into buf 2
  // t = 70
  asm volatile("s_waitcnt vmcnt(6)" ::: "memory");
  __builtin_amdgcn_s_barrier();
  asm volatile("" ::: "memory");
  step(1);
  // t = 71
  asm volatile("s_waitcnt vmcnt(0)" ::: "memory");
  __builtin_amdgcn_s_barrier();
  asm volatile("" ::: "memory");
  step(2);
#undef ROUND

  // epilogue: D[row=o][col=pix], col=lane&15, row=(lane>>4)*4+r ; scale alpha
  int nc[4], rc[4];
#pragma unroll
  for (int ni = 0; ni < 4; ++ni) {
    const int pix = pix0 + wn * 64 + ni * 16 + ar;
    nc[ni] = pix / 3136; rc[ni] = pix % 3136;
  }
#pragma unroll
  for (int mi = 0; mi < 8; ++mi) {
    const int orow = wm * 128 + mi * 16 + aq * 4;
    float al[4];
#pragma unroll
    for (int r = 0; r < 4; ++r) al[r] = alpha[orow + r];
#pragma unroll
    for (int ni = 0; ni < 4; ++ni) {
      const size_t base = (size_t)nc[ni] * 802816 + (size_t)orow * 3136 + (size_t)rc[ni];
#pragma unroll
      for (int r = 0; r < 4; ++r)
        out[base + (size_t)r * 3136] = acc[mi][ni][r] * al[r];
    }
  }
}

extern "C" void kernel_launch(void* const* d_in, const int* in_sizes, int n_in,
                              void* d_out, int out_size, void* d_ws, size_t ws_size,
                              hipStream_t stream) {
  const float* x = (const float*)d_in[0];
  const float* w = (const float*)d_in[1];
  char* ws = (char*)d_ws;
  unsigned short* xp  = (unsigned short*)ws;
  unsigned short* wbp = (unsigned short*)(ws + WB_OFF);
  float* alpha = (float*)(ws + AL_OFF);
  float* out = (float*)d_out;

  zero_halo<<<32, 1024, 0, stream>>>(xp);
  prep_w<<<256, 256, 0, stream>>>(w, wbp, alpha);
  prep_x<<<32 * 49, 256, 0, stream>>>(x, xp);
  conv_mfma<<<784, 256, 0, stream>>>(xp, wbp, alpha, out);
}